// Round 11
// baseline (83.875 us; speedup 1.0000x reference)
//
#include <hip/hip_runtime.h>
#include <math.h>

// Problem constants
#define HW 64
#define NB 2
#define NCIN 128
#define NCH 32

typedef float f32x4 __attribute__((ext_vector_type(4)));

// ws layout:
//   fm  : float[2*64*64]   @ 0       (32768 B)
//   pk  : int  [8192]      @ 32768   (32768 B)   packed corner coords
//   wts : float4[8192]     @ 65536   (131072 B)  bilinear*ga weights

// ---------------- kernel 1: fm = mean over 128 channels ----------------
__global__ __launch_bounds__(256) void k_mean(const float* __restrict__ feat,
                                              float* __restrict__ fm) {
    int bh = blockIdx.x;            // b*64 + h
    int w  = threadIdx.x & 63;
    int cg = threadIdx.x >> 6;      // 0..3, each sums 32 channels
    int b = bh >> 6, h = bh & 63;
    const float* base = feat + ((size_t)(b * NCIN) * 64 + h) * 64 + w;
    float s = 0.f;
    #pragma unroll
    for (int c = 0; c < 32; ++c)
        s += base[(size_t)(cg * 32 + c) * 4096];
    __shared__ float red[4][64];
    red[cg][w] = s;
    __syncthreads();
    if (cg == 0) {
        float tot = red[0][w] + red[1][w] + red[2][w] + red[3][w];
        fm[bh * 64 + w] = tot * (1.f / 128.f);
    }
}

// ------------- kernel 2: per-position coords/weights/gain -------------
__global__ __launch_bounds__(256) void k_params(
    const float* __restrict__ fm,
    const float* __restrict__ W_in, const float* __restrict__ b_in,
    const float* __restrict__ W_dw, const float* __restrict__ b_dw,
    const float* __restrict__ W_ofs, const float* __restrict__ W_a,
    const float* __restrict__ b_a, const float* __restrict__ lam,
    int* __restrict__ pk, float4* __restrict__ wts)
{
    __shared__ float WD[NCH * 25];
    __shared__ float Wi[NCH], Bi[NCH], Bd[NCH], Wo0[NCH], Wo1[NCH], Wa_s[NCH];
    int t = threadIdx.x;
    for (int k = t; k < NCH * 25; k += 256) WD[k] = W_dw[k];
    if (t < NCH) {
        Wi[t]  = W_in[t];  Bi[t]  = b_in[t]; Bd[t] = b_dw[t];
        Wo0[t] = W_ofs[t]; Wo1[t] = W_ofs[NCH + t];
        Wa_s[t] = W_a[t];
    }
    __syncthreads();

    int p = blockIdx.x * 256 + t;   // 0..8191
    int b = p >> 12;
    int i = (p >> 6) & 63;
    int j = p & 63;

    // 5x5 replicate-padded patch of fm
    float patch[25];
    #pragma unroll
    for (int dy = 0; dy < 5; ++dy) {
        int ry = i + dy - 2; ry = ry < 0 ? 0 : (ry > 63 ? 63 : ry);
        #pragma unroll
        for (int dx = 0; dx < 5; ++dx) {
            int rx = j + dx - 2; rx = rx < 0 ? 0 : (rx > 63 ? 63 : rx);
            patch[dy * 5 + dx] = fm[(b * 64 + ry) * 64 + rx];
        }
    }
    float fmc = patch[12];

    float a0 = 0.f, a1 = 0.f, kA = 0.f, kB = 0.f;
    for (int c = 0; c < NCH; ++c) {
        float s = 0.f, sw = 0.f;
        #pragma unroll
        for (int q = 0; q < 25; ++q) {
            float wv = WD[c * 25 + q];
            s  += patch[q] * wv;
            sw += wv;
        }
        float pre = Wi[c] * s + Bi[c] * sw + Bd[c];
        float zc = pre > 0.f ? pre : 0.f;
        a0 += zc * Wo0[c];
        a1 += zc * Wo1[c];
        kA += Wi[c] * Wa_s[c];
        kB += Bi[c] * Wa_s[c];
    }
    float ga = 1.f + lam[0] * (fmc * kA + kB + b_a[0]);

    float yy = (i + 0.5f) * (1.f / 32.f) - 1.f;
    float xx = (j + 0.5f) * (1.f / 32.f) - 1.f;
    float pos0 = fminf(fmaxf((100.f / 64.f) * tanhf(a0) + yy, -1.f), 1.f); // y
    float pos1 = fminf(fmaxf((100.f / 64.f) * tanhf(a1) + xx, -1.f), 1.f); // x
    float y = (pos0 + 1.f) * 0.5f * 63.f;
    float x = (pos1 + 1.f) * 0.5f * 63.f;
    float y0 = floorf(y), x0 = floorf(x);
    float wy1 = y - y0, wx1 = x - x0;
    float wy0 = 1.f - wy1, wx0 = 1.f - wx1;
    int y0i = (int)y0; y0i = y0i < 0 ? 0 : (y0i > 63 ? 63 : y0i);
    int x0i = (int)x0; x0i = x0i < 0 ? 0 : (x0i > 63 ? 63 : x0i);
    int y1i = y0i + 1 > 63 ? 63 : y0i + 1;
    int x1i = x0i + 1 > 63 ? 63 : x0i + 1;

    pk[p] = y0i | (y1i << 6) | (x0i << 12) | (x1i << 18);
    wts[p] = make_float4(wy0 * wx0 * ga, wy0 * wx1 * ga,
                         wy1 * wx0 * ga, wy1 * wx1 * ga);
}

// ------------- kernel 3: bbox-staged gather-sample -------------
// block = (bi, ct of 128 ch, jh of 32 j's); 256 threads; LDS 40 KB.
// Stage the UNION of corner cells (bbox rect, typ. 2 x ~34 = ~68 cells,
// each 512 B = the ct's 128-ch slice) ONCE into LDS -> ~1.9x read dedup
// vs per-j corner reads. Data-independent: if bbox > 80 cells, fall back
// to direct global reads (never taken for near-identity grids).
// LDS rotation swizzle: cell c, quad m at c*128 + 4*((m+c)&31)
//   write side (fixed c, m varies): conflict-free
//   read side (fixed q, c varies):  conflict-free / broadcast
__global__ __launch_bounds__(256) void k_sample(
    const float* __restrict__ gauss,
    const int* __restrict__ pk, const float4* __restrict__ wts,
    float* __restrict__ out)
{
    __shared__ float lds[80 * 128];  // 40 KB
    int bid = blockIdx.x;
    // bijective XCD swizzle (R9 mapping): 8192 % 8 == 0
    int swz = (bid & 7) * 1024 + (bid >> 3);
    int bi  = swz >> 6;              // b*64 + i
    int ct  = (swz >> 1) & 31;       // channel tile (128 ch)
    int jh  = swz & 1;               // j half (32 j's)
    int b = bi >> 6, i = bi & 63;
    int c0 = ct * 128;
    int t  = threadIdx.x;
    int pbase = bi * 64 + jh * 32;

    // ---- bbox over the block's 32 j's (wave-reduce; all waves identical) --
    int myj = t & 31;
    int pv  = pk[pbase + myj];
    int py0 = pv & 63, py1 = (pv >> 6) & 63;
    int px0 = (pv >> 12) & 63, px1 = (pv >> 18) & 63;
    int ymin = min(py0, py1), ymax = max(py0, py1);
    int xmin = min(px0, px1), xmax = max(px0, px1);
    #pragma unroll
    for (int d = 1; d <= 16; d <<= 1) {
        ymin = min(ymin, __shfl_xor(ymin, d));
        ymax = max(ymax, __shfl_xor(ymax, d));
        xmin = min(xmin, __shfl_xor(xmin, d));
        xmax = max(xmax, __shfl_xor(xmax, d));
    }
    int W = xmax - xmin + 1;
    int H = ymax - ymin + 1;
    int ncell = W * H;

    const float* gbase = gauss + (size_t)b * 16777216 + c0;
    float4 wt = wts[pbase + myj];
    size_t obase = (size_t)b * 16777216 + (size_t)c0 * 4096
                 + (size_t)i * 64 + jh * 32 + myj;
    int cg = t >> 5;                 // 0..7 -> handles ch-quads m*8+cg

    if (ncell <= 80) {
        // ---- stage bbox cells (512 B each), coalesced 2-segment loads ----
        int nquad = ncell << 5;      // ncell * 32 f32x4 quads
        for (int kq = t; kq < nquad; kq += 256) {
            int cell = kq >> 5, m = kq & 31;
            int cy = ymin + cell / W, cx = xmin + cell % W;
            f32x4 v = *(const f32x4*)(gbase + (size_t)(cy * 64 + cx) * 4096 + 4 * m);
            *(f32x4*)&lds[cell * 128 + 4 * ((m + cell) & 31)] = v;
        }
        __syncthreads();

        // ---- combine from LDS + coalesced NT stores ----
        int ca = (py0 - ymin) * W + (px0 - xmin);
        int cb = (py0 - ymin) * W + (px1 - xmin);
        int cc = (py1 - ymin) * W + (px0 - xmin);
        int cd = (py1 - ymin) * W + (px1 - xmin);
        #pragma unroll
        for (int m = 0; m < 4; ++m) {
            int q = m * 8 + cg;      // channel quad 0..31
            f32x4 A = *(const f32x4*)&lds[ca * 128 + 4 * ((q + ca) & 31)];
            f32x4 B = *(const f32x4*)&lds[cb * 128 + 4 * ((q + cb) & 31)];
            f32x4 C = *(const f32x4*)&lds[cc * 128 + 4 * ((q + cc) & 31)];
            f32x4 D = *(const f32x4*)&lds[cd * 128 + 4 * ((q + cd) & 31)];
            f32x4 res = wt.x * A + wt.y * B + wt.z * C + wt.w * D;
            float* po = out + obase + (size_t)(q * 4) * 4096;
            __builtin_nontemporal_store(res.x, po);
            __builtin_nontemporal_store(res.y, po + 4096);
            __builtin_nontemporal_store(res.z, po + 8192);
            __builtin_nontemporal_store(res.w, po + 12288);
        }
    } else {
        // ---- fallback: direct global corner reads (arbitrary data) ----
        size_t fa = (size_t)(py0 * 64 + px0) * 4096;
        size_t fb = (size_t)(py0 * 64 + px1) * 4096;
        size_t fc = (size_t)(py1 * 64 + px0) * 4096;
        size_t fd = (size_t)(py1 * 64 + px1) * 4096;
        #pragma unroll
        for (int m = 0; m < 4; ++m) {
            int q = m * 8 + cg;
            f32x4 A = *(const f32x4*)(gbase + fa + 4 * q);
            f32x4 B = *(const f32x4*)(gbase + fb + 4 * q);
            f32x4 C = *(const f32x4*)(gbase + fc + 4 * q);
            f32x4 D = *(const f32x4*)(gbase + fd + 4 * q);
            f32x4 res = wt.x * A + wt.y * B + wt.z * C + wt.w * D;
            float* po = out + obase + (size_t)(q * 4) * 4096;
            __builtin_nontemporal_store(res.x, po);
            __builtin_nontemporal_store(res.y, po + 4096);
            __builtin_nontemporal_store(res.z, po + 8192);
            __builtin_nontemporal_store(res.w, po + 12288);
        }
    }
}

extern "C" void kernel_launch(void* const* d_in, const int* in_sizes, int n_in,
                              void* d_out, int out_size, void* d_ws, size_t ws_size,
                              hipStream_t stream) {
    const float* feat  = (const float*)d_in[0];
    const float* gauss = (const float*)d_in[1];
    const float* W_in  = (const float*)d_in[2];
    const float* b_in  = (const float*)d_in[3];
    const float* W_dw  = (const float*)d_in[4];
    const float* b_dw  = (const float*)d_in[5];
    const float* W_ofs = (const float*)d_in[6];
    const float* W_a   = (const float*)d_in[7];
    const float* b_a   = (const float*)d_in[8];
    const float* lam   = (const float*)d_in[9];
    float* out = (float*)d_out;

    float*  fm  = (float*)d_ws;
    int*    pk  = (int*)((char*)d_ws + 32768);
    float4* wts = (float4*)((char*)d_ws + 65536);

    k_mean  <<<NB * HW, 256, 0, stream>>>(feat, fm);
    k_params<<<32, 256, 0, stream>>>(fm, W_in, b_in, W_dw, b_dw,
                                     W_ofs, W_a, b_a, lam, pk, wts);
    k_sample<<<NB * HW * 64, 256, 0, stream>>>(gauss, pk, wts, out);
}

// Round 12
// 78.694 us; speedup vs baseline: 1.0658x; 1.0658x over previous
//
#include <hip/hip_runtime.h>
#include <math.h>

// Problem constants
#define HW 64
#define NB 2
#define NCIN 128
#define NCH 32

typedef float f32x4 __attribute__((ext_vector_type(4)));

typedef __attribute__((address_space(3))) void lds_void;
typedef const __attribute__((address_space(1))) void g_void;
__device__ __forceinline__ void load_lds16(const float* g, float* l) {
    __builtin_amdgcn_global_load_lds((g_void*)g, (lds_void*)l, 16, 0, 0);
}

// ws layout:
//   fm   : float[2*64*64]            @ 0        (32768 B)
//   offs : int4 [8192]               @ 32768    (131072 B)
//   wts  : float4[8192]              @ 163840   (131072 B)

// ---------------- kernel 1: fm = mean over 128 channels ----------------
__global__ __launch_bounds__(256) void k_mean(const float* __restrict__ feat,
                                              float* __restrict__ fm) {
    int bh = blockIdx.x;            // b*64 + h
    int w  = threadIdx.x & 63;
    int cg = threadIdx.x >> 6;      // 0..3, each sums 32 channels
    int b = bh >> 6, h = bh & 63;
    const float* base = feat + ((size_t)(b * NCIN) * 64 + h) * 64 + w;
    float s = 0.f;
    #pragma unroll
    for (int c = 0; c < 32; ++c)
        s += base[(size_t)(cg * 32 + c) * 4096];
    __shared__ float red[4][64];
    red[cg][w] = s;
    __syncthreads();
    if (cg == 0) {
        float tot = red[0][w] + red[1][w] + red[2][w] + red[3][w];
        fm[bh * 64 + w] = tot * (1.f / 128.f);
    }
}

// ------------- kernel 2: per-position offsets/weights/gain -------------
__global__ __launch_bounds__(256) void k_params(
    const float* __restrict__ fm,
    const float* __restrict__ W_in, const float* __restrict__ b_in,
    const float* __restrict__ W_dw, const float* __restrict__ b_dw,
    const float* __restrict__ W_ofs, const float* __restrict__ W_a,
    const float* __restrict__ b_a, const float* __restrict__ lam,
    int4* __restrict__ offs, float4* __restrict__ wts)
{
    __shared__ float WD[NCH * 25];
    __shared__ float Wi[NCH], Bi[NCH], Bd[NCH], Wo0[NCH], Wo1[NCH], Wa_s[NCH];
    int t = threadIdx.x;
    for (int k = t; k < NCH * 25; k += 256) WD[k] = W_dw[k];
    if (t < NCH) {
        Wi[t]  = W_in[t];  Bi[t]  = b_in[t]; Bd[t] = b_dw[t];
        Wo0[t] = W_ofs[t]; Wo1[t] = W_ofs[NCH + t];
        Wa_s[t] = W_a[t];
    }
    __syncthreads();

    int p = blockIdx.x * 256 + t;   // 0..8191
    int b = p >> 12;
    int i = (p >> 6) & 63;
    int j = p & 63;

    // 5x5 replicate-padded patch of fm
    float patch[25];
    #pragma unroll
    for (int dy = 0; dy < 5; ++dy) {
        int ry = i + dy - 2; ry = ry < 0 ? 0 : (ry > 63 ? 63 : ry);
        #pragma unroll
        for (int dx = 0; dx < 5; ++dx) {
            int rx = j + dx - 2; rx = rx < 0 ? 0 : (rx > 63 ? 63 : rx);
            patch[dy * 5 + dx] = fm[(b * 64 + ry) * 64 + rx];
        }
    }
    float fmc = patch[12];

    float a0 = 0.f, a1 = 0.f, kA = 0.f, kB = 0.f;
    for (int c = 0; c < NCH; ++c) {
        float s = 0.f, sw = 0.f;
        #pragma unroll
        for (int q = 0; q < 25; ++q) {
            float wv = WD[c * 25 + q];
            s  += patch[q] * wv;
            sw += wv;
        }
        float pre = Wi[c] * s + Bi[c] * sw + Bd[c];
        float zc = pre > 0.f ? pre : 0.f;
        a0 += zc * Wo0[c];
        a1 += zc * Wo1[c];
        kA += Wi[c] * Wa_s[c];
        kB += Bi[c] * Wa_s[c];
    }
    float ga = 1.f + lam[0] * (fmc * kA + kB + b_a[0]);

    float yy = (i + 0.5f) * (1.f / 32.f) - 1.f;
    float xx = (j + 0.5f) * (1.f / 32.f) - 1.f;
    float pos0 = fminf(fmaxf((100.f / 64.f) * tanhf(a0) + yy, -1.f), 1.f); // y
    float pos1 = fminf(fmaxf((100.f / 64.f) * tanhf(a1) + xx, -1.f), 1.f); // x
    float y = (pos0 + 1.f) * 0.5f * 63.f;
    float x = (pos1 + 1.f) * 0.5f * 63.f;
    float y0 = floorf(y), x0 = floorf(x);
    float wy1 = y - y0, wx1 = x - x0;
    float wy0 = 1.f - wy1, wx0 = 1.f - wx1;
    int y0i = (int)y0; y0i = y0i < 0 ? 0 : (y0i > 63 ? 63 : y0i);
    int x0i = (int)x0; x0i = x0i < 0 ? 0 : (x0i > 63 ? 63 : x0i);
    int y1i = y0i + 1 > 63 ? 63 : y0i + 1;
    int x1i = x0i + 1 > 63 ? 63 : x0i + 1;

    int basep = b * 16777216;
    offs[p] = make_int4(basep + (y0i * 64 + x0i) * 4096,
                        basep + (y0i * 64 + x1i) * 4096,
                        basep + (y1i * 64 + x0i) * 4096,
                        basep + (y1i * 64 + x1i) * 4096);
    wts[p] = make_float4(wy0 * wx0 * ga, wy0 * wx1 * ga,
                         wy1 * wx0 * ga, wy1 * wx1 * ga);
}

// ------------- kernel 3: DMA-staged gather-sample -------------
// block = (bi, ct of 256 ch, jq of 16 j's); 256 threads; LDS 64 KB.
// phase1: 64 slices (16 j x 4 corners), each = 1 KB contiguous cell-slice
//         staged by ONE global_load_lds(16B) per wave (m97 shape: no VGPR
//         dest -> wave queues 16 DMAs back-to-back, ~16 KB in flight/wave).
//         Bank swizzle via per-lane GLOBAL source rotation (lane+j2)&63;
//         LDS stays linear (HW: dest = uniform base + lane*16).
// phase2: thread (j2=t&15, cg=t>>4): 4x {4 ds_read_b128 + combine + 4 NT
//         scalar stores, 64-B contiguous segments}.
__global__ __launch_bounds__(256) void k_sample(
    const float* __restrict__ gauss,
    const int4* __restrict__ offs, const float4* __restrict__ wts,
    float* __restrict__ out)
{
    __shared__ float lds[64 * 256];   // 64 KB: slice s at floats [s*256, +256)
    int bid = blockIdx.x;
    // bijective XCD swizzle: 8192 % 8 == 0; within XCD: jq fast, ct, bi slow
    int swz = (bid & 7) * 1024 + (bid >> 3);
    int bi  = swz >> 6;              // b*64 + i  (0..127)
    int ct  = (swz >> 2) & 15;       // channel tile of 256 ch
    int jq  = swz & 3;               // j quarter (16 j's)
    int b = bi >> 6, i = bi & 63;
    int c0 = ct * 256;
    int t  = threadIdx.x;
    int pbase = bi * 64 + jq * 16;

    // ---- phase 1: 16 DMA slices per wave ----
    int w    = t >> 6;               // wave 0..3
    int lane = t & 63;
    #pragma unroll
    for (int r = 0; r < 16; ++r) {
        int s  = w * 16 + r;         // slice 0..63 (wave-uniform)
        int j2 = s >> 2;             // 0..15
        int4 o = offs[pbase + j2];
        int corner = r & 3;          // compile-time per unrolled iter
        int offsel = corner == 0 ? o.x : corner == 1 ? o.y
                   : corner == 2 ? o.z : o.w;
        const float* gp = gauss + (size_t)offsel + c0
                        + 4 * ((lane + j2) & 63);   // rotated source quad
        load_lds16(gp, &lds[s * 256]);
    }
    __syncthreads();   // drains vmcnt(0) for all waves' DMAs

    // ---- phase 2: combine + coalesced NT stores ----
    int j2 = t & 15;
    int cg = t >> 4;                 // 0..15
    float4 wt = wts[pbase + j2];
    size_t obase = (size_t)b * 16777216 + (size_t)c0 * 4096
                 + (size_t)i * 64 + jq * 16 + j2;
    int sbase = j2 * 1024;           // 4 slices x 256 floats
    #pragma unroll
    for (int m = 0; m < 4; ++m) {
        int q = m * 16 + cg;         // channel quad 0..63
        int pos = 4 * ((q - j2) & 63);
        f32x4 A = *(const f32x4*)&lds[sbase +        pos];
        f32x4 B = *(const f32x4*)&lds[sbase +  256 + pos];
        f32x4 C = *(const f32x4*)&lds[sbase +  512 + pos];
        f32x4 D = *(const f32x4*)&lds[sbase +  768 + pos];
        f32x4 res = wt.x * A + wt.y * B + wt.z * C + wt.w * D;
        float* po = out + obase + (size_t)(4 * q) * 4096;
        __builtin_nontemporal_store(res.x, po);
        __builtin_nontemporal_store(res.y, po + 4096);
        __builtin_nontemporal_store(res.z, po + 8192);
        __builtin_nontemporal_store(res.w, po + 12288);
    }
}

extern "C" void kernel_launch(void* const* d_in, const int* in_sizes, int n_in,
                              void* d_out, int out_size, void* d_ws, size_t ws_size,
                              hipStream_t stream) {
    const float* feat  = (const float*)d_in[0];
    const float* gauss = (const float*)d_in[1];
    const float* W_in  = (const float*)d_in[2];
    const float* b_in  = (const float*)d_in[3];
    const float* W_dw  = (const float*)d_in[4];
    const float* b_dw  = (const float*)d_in[5];
    const float* W_ofs = (const float*)d_in[6];
    const float* W_a   = (const float*)d_in[7];
    const float* b_a   = (const float*)d_in[8];
    const float* lam   = (const float*)d_in[9];
    float* out = (float*)d_out;

    float* fm   = (float*)d_ws;
    int4*  offs = (int4*)((char*)d_ws + 32768);
    float4* wts = (float4*)((char*)d_ws + 32768 + 131072);

    k_mean  <<<NB * HW, 256, 0, stream>>>(feat, fm);
    k_params<<<32, 256, 0, stream>>>(fm, W_in, b_in, W_dw, b_dw,
                                     W_ofs, W_a, b_a, lam, offs, wts);
    k_sample<<<NB * HW * 64, 256, 0, stream>>>(gauss, offs, wts, out);
}

// Round 13
// 72.974 us; speedup vs baseline: 1.1494x; 1.0784x over previous
//
#include <hip/hip_runtime.h>
#include <math.h>

// Problem constants
#define HW 64
#define NB 2
#define NCIN 128
#define NCH 32

typedef float f32x4 __attribute__((ext_vector_type(4)));

// ws layout:
//   fm  : float[2*64*64]   @ 0       (32768 B)
//   pk  : int  [8192]      @ 32768   (32768 B)   packed corner coords
//   wts : float4[8192]     @ 65536   (131072 B)  bilinear*ga weights

// ---------------- kernel 1: fm = mean over 128 channels ----------------
__global__ __launch_bounds__(256) void k_mean(const float* __restrict__ feat,
                                              float* __restrict__ fm) {
    int bh = blockIdx.x;            // b*64 + h
    int w  = threadIdx.x & 63;
    int cg = threadIdx.x >> 6;      // 0..3, each sums 32 channels
    int b = bh >> 6, h = bh & 63;
    const float* base = feat + ((size_t)(b * NCIN) * 64 + h) * 64 + w;
    float s = 0.f;
    #pragma unroll
    for (int c = 0; c < 32; ++c)
        s += base[(size_t)(cg * 32 + c) * 4096];
    __shared__ float red[4][64];
    red[cg][w] = s;
    __syncthreads();
    if (cg == 0) {
        float tot = red[0][w] + red[1][w] + red[2][w] + red[3][w];
        fm[bh * 64 + w] = tot * (1.f / 128.f);
    }
}

// ------------- kernel 2: per-position coords/weights/gain -------------
__global__ __launch_bounds__(256) void k_params(
    const float* __restrict__ fm,
    const float* __restrict__ W_in, const float* __restrict__ b_in,
    const float* __restrict__ W_dw, const float* __restrict__ b_dw,
    const float* __restrict__ W_ofs, const float* __restrict__ W_a,
    const float* __restrict__ b_a, const float* __restrict__ lam,
    int* __restrict__ pk, float4* __restrict__ wts)
{
    __shared__ float WD[NCH * 25];
    __shared__ float Wi[NCH], Bi[NCH], Bd[NCH], Wo0[NCH], Wo1[NCH], Wa_s[NCH];
    int t = threadIdx.x;
    for (int k = t; k < NCH * 25; k += 256) WD[k] = W_dw[k];
    if (t < NCH) {
        Wi[t]  = W_in[t];  Bi[t]  = b_in[t]; Bd[t] = b_dw[t];
        Wo0[t] = W_ofs[t]; Wo1[t] = W_ofs[NCH + t];
        Wa_s[t] = W_a[t];
    }
    __syncthreads();

    int p = blockIdx.x * 256 + t;   // 0..8191
    int b = p >> 12;
    int i = (p >> 6) & 63;
    int j = p & 63;

    // 5x5 replicate-padded patch of fm
    float patch[25];
    #pragma unroll
    for (int dy = 0; dy < 5; ++dy) {
        int ry = i + dy - 2; ry = ry < 0 ? 0 : (ry > 63 ? 63 : ry);
        #pragma unroll
        for (int dx = 0; dx < 5; ++dx) {
            int rx = j + dx - 2; rx = rx < 0 ? 0 : (rx > 63 ? 63 : rx);
            patch[dy * 5 + dx] = fm[(b * 64 + ry) * 64 + rx];
        }
    }
    float fmc = patch[12];

    float a0 = 0.f, a1 = 0.f, kA = 0.f, kB = 0.f;
    for (int c = 0; c < NCH; ++c) {
        float s = 0.f, sw = 0.f;
        #pragma unroll
        for (int q = 0; q < 25; ++q) {
            float wv = WD[c * 25 + q];
            s  += patch[q] * wv;
            sw += wv;
        }
        float pre = Wi[c] * s + Bi[c] * sw + Bd[c];
        float zc = pre > 0.f ? pre : 0.f;
        a0 += zc * Wo0[c];
        a1 += zc * Wo1[c];
        kA += Wi[c] * Wa_s[c];
        kB += Bi[c] * Wa_s[c];
    }
    float ga = 1.f + lam[0] * (fmc * kA + kB + b_a[0]);

    float yy = (i + 0.5f) * (1.f / 32.f) - 1.f;
    float xx = (j + 0.5f) * (1.f / 32.f) - 1.f;
    float pos0 = fminf(fmaxf((100.f / 64.f) * tanhf(a0) + yy, -1.f), 1.f); // y
    float pos1 = fminf(fmaxf((100.f / 64.f) * tanhf(a1) + xx, -1.f), 1.f); // x
    float y = (pos0 + 1.f) * 0.5f * 63.f;
    float x = (pos1 + 1.f) * 0.5f * 63.f;
    float y0 = floorf(y), x0 = floorf(x);
    float wy1 = y - y0, wx1 = x - x0;
    float wy0 = 1.f - wy1, wx0 = 1.f - wx1;
    int y0i = (int)y0; y0i = y0i < 0 ? 0 : (y0i > 63 ? 63 : y0i);
    int x0i = (int)x0; x0i = x0i < 0 ? 0 : (x0i > 63 ? 63 : x0i);
    int y1i = y0i + 1 > 63 ? 63 : y0i + 1;
    int x1i = x0i + 1 > 63 ? 63 : x0i + 1;

    pk[p] = y0i | (y1i << 6) | (x0i << 12) | (x1i << 18);
    wts[p] = make_float4(wy0 * wx0 * ga, wy0 * wx1 * ga,
                         wy1 * wx0 * ga, wy1 * wx1 * ga);
}

// ------------- kernel 3: row-staged gather-sample (volume dedup) -------------
// block = (bi, ct of 64 ch); covers ALL 64 j of one output row; 256 threads.
// Wave-reduce [ymin..ymax1] over the row's corners (H = 2..3 rows for
// near-identity grids); stage H x 64 cells (256 B ch-slices) ONCE into LDS
// (H*16 KB vs 64 KB consumed -> up to 2x read dedup); shift/mask addressing
// only (R11's div/mod in the address chain was its failure). Block-uniform
// fallback to direct reads if H > 3 (arbitrary data; never taken here).
// LDS swizzle: cell (slot s, col x), quad m at (s*64+x)*64 + 4*((m+x)&15)
__global__ __launch_bounds__(256) void k_sample(
    const float* __restrict__ gauss,
    const int* __restrict__ pk, const float4* __restrict__ wts,
    float* __restrict__ out)
{
    __shared__ float lds[3 * 64 * 64];   // 48 KB
    int bid = blockIdx.x;
    // bijective XCD swizzle: 8192 % 8 == 0; ct fast, bi slow within XCD
    int swz = (bid & 7) * 1024 + (bid >> 3);
    int bi  = swz >> 6;              // b*64 + i  (0..127)
    int ct  = swz & 63;              // channel tile of 64 ch
    int b = bi >> 6, i = bi & 63;
    int c0 = ct * 64;
    int t  = threadIdx.x;
    int pbase = bi * 64;

    // ---- row bounds: every wave reduces over all 64 j ----
    int lane = t & 63;
    int pv   = pk[pbase + lane];
    int y0l = pv & 63, y1l = (pv >> 6) & 63;
    int x0l = (pv >> 12) & 63, x1l = (pv >> 18) & 63;
    int ymin = y0l, ymax = y1l;
    #pragma unroll
    for (int d = 1; d < 64; d <<= 1) {
        ymin = min(ymin, __shfl_xor(ymin, d));
        ymax = max(ymax, __shfl_xor(ymax, d));
    }
    int H = ymax - ymin + 1;

    const float* gb = gauss + (size_t)b * 16777216 + c0;
    // phase-2 identity: this thread handles j = lane, quads m*4+qg
    int qg = t >> 6;                 // 0..3
    float4 wt = wts[pbase + lane];
    size_t obase = (size_t)b * 16777216 + (size_t)c0 * 4096
                 + (size_t)i * 64 + lane;

    if (H <= 3) {
        // ---- stage H*64 cells, shift/mask addresses only ----
        int nr = 4 * H;              // wave-uniform trip count (8 or 12)
        for (int r = 0; r < nr; ++r) {
            int idx  = r * 256 + t;
            int m    = idx & 15;     // quad within 256-B slice
            int cell = idx >> 4;     // 0 .. H*64-1
            int row  = ymin + (cell >> 6);
            int col  = cell & 63;
            f32x4 v = *(const f32x4*)(gb + (size_t)((row * 64 + col) * 4096) + 4 * m);
            *(f32x4*)&lds[cell * 64 + 4 * ((m + col) & 15)] = v;
        }
        __syncthreads();

        // ---- combine from LDS + coalesced NT stores ----
        int sa = (y0l - ymin) * 64, sc = (y1l - ymin) * 64;
        int ca = sa + x0l, cb = sa + x1l, cc = sc + x0l, cd = sc + x1l;
        #pragma unroll
        for (int m = 0; m < 4; ++m) {
            int q = m * 4 + qg;      // channel quad 0..15
            f32x4 A = *(const f32x4*)&lds[ca * 64 + 4 * ((q + x0l) & 15)];
            f32x4 B = *(const f32x4*)&lds[cb * 64 + 4 * ((q + x1l) & 15)];
            f32x4 C = *(const f32x4*)&lds[cc * 64 + 4 * ((q + x0l) & 15)];
            f32x4 D = *(const f32x4*)&lds[cd * 64 + 4 * ((q + x1l) & 15)];
            f32x4 res = wt.x * A + wt.y * B + wt.z * C + wt.w * D;
            float* po = out + obase + (size_t)(4 * q) * 4096;
            __builtin_nontemporal_store(res.x, po);
            __builtin_nontemporal_store(res.y, po + 4096);
            __builtin_nontemporal_store(res.z, po + 8192);
            __builtin_nontemporal_store(res.w, po + 12288);
        }
    } else {
        // ---- fallback: direct global corner reads (arbitrary data) ----
        size_t fa = (size_t)((y0l * 64 + x0l) * 4096);
        size_t fb = (size_t)((y0l * 64 + x1l) * 4096);
        size_t fc = (size_t)((y1l * 64 + x0l) * 4096);
        size_t fd = (size_t)((y1l * 64 + x1l) * 4096);
        #pragma unroll
        for (int m = 0; m < 4; ++m) {
            int q = m * 4 + qg;
            f32x4 A = *(const f32x4*)(gb + fa + 4 * q);
            f32x4 B = *(const f32x4*)(gb + fb + 4 * q);
            f32x4 C = *(const f32x4*)(gb + fc + 4 * q);
            f32x4 D = *(const f32x4*)(gb + fd + 4 * q);
            f32x4 res = wt.x * A + wt.y * B + wt.z * C + wt.w * D;
            float* po = out + obase + (size_t)(4 * q) * 4096;
            __builtin_nontemporal_store(res.x, po);
            __builtin_nontemporal_store(res.y, po + 4096);
            __builtin_nontemporal_store(res.z, po + 8192);
            __builtin_nontemporal_store(res.w, po + 12288);
        }
    }
}

extern "C" void kernel_launch(void* const* d_in, const int* in_sizes, int n_in,
                              void* d_out, int out_size, void* d_ws, size_t ws_size,
                              hipStream_t stream) {
    const float* feat  = (const float*)d_in[0];
    const float* gauss = (const float*)d_in[1];
    const float* W_in  = (const float*)d_in[2];
    const float* b_in  = (const float*)d_in[3];
    const float* W_dw  = (const float*)d_in[4];
    const float* b_dw  = (const float*)d_in[5];
    const float* W_ofs = (const float*)d_in[6];
    const float* W_a   = (const float*)d_in[7];
    const float* b_a   = (const float*)d_in[8];
    const float* lam   = (const float*)d_in[9];
    float* out = (float*)d_out;

    float*  fm  = (float*)d_ws;
    int*    pk  = (int*)((char*)d_ws + 32768);
    float4* wts = (float4*)((char*)d_ws + 65536);

    k_mean  <<<NB * HW, 256, 0, stream>>>(feat, fm);
    k_params<<<32, 256, 0, stream>>>(fm, W_in, b_in, W_dw, b_dw,
                                     W_ofs, W_a, b_a, lam, pk, wts);
    k_sample<<<NB * HW * 64, 256, 0, stream>>>(gauss, pk, wts, out);
}

// Round 14
// 68.066 us; speedup vs baseline: 1.2323x; 1.0721x over previous
//
#include <hip/hip_runtime.h>
#include <math.h>

// Problem constants
#define HW 64
#define NB 2
#define NCIN 128
#define NCH 32

typedef float f32x4 __attribute__((ext_vector_type(4)));

// ws layout:
//   (unused)                         @ 0        (32768 B)
//   offs : int4 [8192]               @ 32768    (131072 B)
//   wts  : float4[8192]              @ 163840   (131072 B)

// ------------- kernel 1 (fused): fm rows + offsets/weights/gain -------------
// 32 blocks x 256 threads; block covers 256 consecutive positions =
// 4 output rows of one b. Each block recomputes the 8 fm rows its 5x5
// patches touch (rows i0-2 .. i0+5, replicate-clamped) directly from feat:
// coalesced 256-B reads, ~8 MB total — cheaper than a separate kernel launch.
__global__ __launch_bounds__(256) void k_params(
    const float* __restrict__ feat,
    const float* __restrict__ W_in, const float* __restrict__ b_in,
    const float* __restrict__ W_dw, const float* __restrict__ b_dw,
    const float* __restrict__ W_ofs, const float* __restrict__ W_a,
    const float* __restrict__ b_a, const float* __restrict__ lam,
    int4* __restrict__ offs, float4* __restrict__ wts)
{
    __shared__ float WD[NCH * 25];
    __shared__ float Wi[NCH], Bi[NCH], Bd[NCH], Wo0[NCH], Wo1[NCH], Wa_s[NCH];
    __shared__ float fmr[8][64];     // fm rows i0-2 .. i0+5 (clamped)
    int t = threadIdx.x;
    for (int k = t; k < NCH * 25; k += 256) WD[k] = W_dw[k];
    if (t < NCH) {
        Wi[t]  = W_in[t];  Bi[t]  = b_in[t]; Bd[t] = b_dw[t];
        Wo0[t] = W_ofs[t]; Wo1[t] = W_ofs[NCH + t];
        Wa_s[t] = W_a[t];
    }

    int p0 = blockIdx.x * 256;
    int b  = p0 >> 12;
    int i0 = (p0 >> 6) & 63;
    // ---- compute the 8 needed fm rows from feat ----
    {
        int col = t & 63, rg = t >> 6;      // rg 0..3
        const float* fb = feat + (size_t)b * (NCIN * 4096) + col;
        #pragma unroll
        for (int rr = 0; rr < 2; ++rr) {
            int row = rg + rr * 4;          // 0..7
            int ri = i0 - 2 + row;
            ri = ri < 0 ? 0 : (ri > 63 ? 63 : ri);
            const float* fp = fb + ri * 64;
            float s = 0.f;
            #pragma unroll 8
            for (int c = 0; c < NCIN; ++c)
                s += fp[(size_t)c * 4096];
            fmr[row][col] = s * (1.f / 128.f);
        }
    }
    __syncthreads();

    int p = p0 + t;                 // 0..8191
    int i = (p >> 6) & 63;
    int j = p & 63;
    int il = i - i0;                // 0..3

    // 5x5 replicate-padded patch of fm (rows from fmr: row = il + dy)
    float patch[25];
    #pragma unroll
    for (int dy = 0; dy < 5; ++dy) {
        #pragma unroll
        for (int dx = 0; dx < 5; ++dx) {
            int rx = j + dx - 2; rx = rx < 0 ? 0 : (rx > 63 ? 63 : rx);
            patch[dy * 5 + dx] = fmr[il + dy][rx];
        }
    }
    float fmc = patch[12];

    float a0 = 0.f, a1 = 0.f, kA = 0.f, kB = 0.f;
    for (int c = 0; c < NCH; ++c) {
        float s = 0.f, sw = 0.f;
        #pragma unroll
        for (int q = 0; q < 25; ++q) {
            float wv = WD[c * 25 + q];
            s  += patch[q] * wv;
            sw += wv;
        }
        float pre = Wi[c] * s + Bi[c] * sw + Bd[c];
        float zc = pre > 0.f ? pre : 0.f;
        a0 += zc * Wo0[c];
        a1 += zc * Wo1[c];
        kA += Wi[c] * Wa_s[c];
        kB += Bi[c] * Wa_s[c];
    }
    float ga = 1.f + lam[0] * (fmc * kA + kB + b_a[0]);

    float yy = (i + 0.5f) * (1.f / 32.f) - 1.f;
    float xx = (j + 0.5f) * (1.f / 32.f) - 1.f;
    float pos0 = fminf(fmaxf((100.f / 64.f) * tanhf(a0) + yy, -1.f), 1.f); // y
    float pos1 = fminf(fmaxf((100.f / 64.f) * tanhf(a1) + xx, -1.f), 1.f); // x
    float y = (pos0 + 1.f) * 0.5f * 63.f;
    float x = (pos1 + 1.f) * 0.5f * 63.f;
    float y0 = floorf(y), x0 = floorf(x);
    float wy1 = y - y0, wx1 = x - x0;
    float wy0 = 1.f - wy1, wx0 = 1.f - wx1;
    int y0i = (int)y0; y0i = y0i < 0 ? 0 : (y0i > 63 ? 63 : y0i);
    int x0i = (int)x0; x0i = x0i < 0 ? 0 : (x0i > 63 ? 63 : x0i);
    int y1i = y0i + 1 > 63 ? 63 : y0i + 1;
    int x1i = x0i + 1 > 63 ? 63 : x0i + 1;

    int basep = b * 16777216;
    offs[p] = make_int4(basep + (y0i * 64 + x0i) * 4096,
                        basep + (y0i * 64 + x1i) * 4096,
                        basep + (y1i * 64 + x0i) * 4096,
                        basep + (y1i * 64 + x1i) * 4096);
    wts[p] = make_float4(wy0 * wx0 * ga, wy0 * wx1 * ga,
                         wy1 * wx0 * ga, wy1 * wx1 * ga);
}

// ------------- kernel 2: gather-sample, 128-channel tile (R6, best) -------------
// block = (b, i, channel-tile of 128); 256 threads; LDS 32 KB XOR-swizzled.
// phase1: thread (h=t&31 -> ch quad 4h, js=t>>5 -> 8 j's): per corner load is
//         512 B contiguous over 32 lanes => 2 segments per wave-instr; 8 iters.
// phase2: thread (j=t&63, cq0=t>>6): b128 LDS read + 4x 256-B NT stores.
// LDS swizzle: word(j, C) = j*128 + 4*(C ^ (j&7))   (C = channel quad 0..31)
__global__ __launch_bounds__(256) void k_sample(
    const float* __restrict__ gauss,
    const int4* __restrict__ offs, const float4* __restrict__ wts,
    float* __restrict__ out)
{
    __shared__ float lds[128 * 64];  // 32 KB exact, swizzled (no pad)
    int bid = blockIdx.x;
    // bijective XCD swizzle: 4096 % 8 == 0; same-bi tiles land on one XCD
    int swz = (bid & 7) * 512 + (bid >> 3);
    int ct = swz & 31;              // channel tile (128 channels)
    int bi = swz >> 5;              // b*64 + i
    int b = bi >> 6, i = bi & 63;
    int c0 = ct * 128;
    int t  = threadIdx.x;
    int pbase = bi * 64;

    int h  = t & 31;                // channel quad: channels 4h..4h+3
    int js = t >> 5;                // 0..7

    #pragma unroll
    for (int r = 0; r < 8; ++r) {
        int j = r * 8 + js;
        int4  off = offs[pbase + j];
        float4 wt = wts[pbase + j];
        f32x4 A = *((const f32x4*)(gauss + off.x + c0) + h);
        f32x4 B = *((const f32x4*)(gauss + off.y + c0) + h);
        f32x4 C = *((const f32x4*)(gauss + off.z + c0) + h);
        f32x4 D = *((const f32x4*)(gauss + off.w + c0) + h);
        f32x4 res = wt.x * A + wt.y * B + wt.z * C + wt.w * D;
        *(f32x4*)&lds[j * 128 + 4 * (h ^ (j & 7))] = res;
    }
    __syncthreads();

    // phase 2: out[b, c0+4*cquad+q, i, 0..63], 256-B contiguous per instr
    size_t obase = (size_t)b * 16777216 + (size_t)c0 * 4096 + (size_t)i * 64;
    int j   = t & 63;
    int cq0 = t >> 6;               // 0..3
    #pragma unroll
    for (int m = 0; m < 8; ++m) {
        int cquad = m * 4 + cq0;    // 0..31
        f32x4 v = *(const f32x4*)&lds[j * 128 + 4 * (cquad ^ (j & 7))];
        float* po = out + obase + (size_t)(4 * cquad) * 4096 + j;
        __builtin_nontemporal_store(v.x, po);
        __builtin_nontemporal_store(v.y, po + 4096);
        __builtin_nontemporal_store(v.z, po + 8192);
        __builtin_nontemporal_store(v.w, po + 12288);
    }
}

extern "C" void kernel_launch(void* const* d_in, const int* in_sizes, int n_in,
                              void* d_out, int out_size, void* d_ws, size_t ws_size,
                              hipStream_t stream) {
    const float* feat  = (const float*)d_in[0];
    const float* gauss = (const float*)d_in[1];
    const float* W_in  = (const float*)d_in[2];
    const float* b_in  = (const float*)d_in[3];
    const float* W_dw  = (const float*)d_in[4];
    const float* b_dw  = (const float*)d_in[5];
    const float* W_ofs = (const float*)d_in[6];
    const float* W_a   = (const float*)d_in[7];
    const float* b_a   = (const float*)d_in[8];
    const float* lam   = (const float*)d_in[9];
    float* out = (float*)d_out;

    int4*   offs = (int4*)((char*)d_ws + 32768);
    float4* wts  = (float4*)((char*)d_ws + 32768 + 131072);

    k_params<<<32, 256, 0, stream>>>(feat, W_in, b_in, W_dw, b_dw,
                                     W_ofs, W_a, b_a, lam, offs, wts);
    k_sample<<<NB * HW * 32, 256, 0, stream>>>(gauss, offs, wts, out);
}